// Round 3
// baseline (10126.077 us; speedup 1.0000x reference)
//
#include <hip/hip_runtime.h>
#include <type_traits>

typedef __bf16 bf16;
typedef float f32x4 __attribute__((ext_vector_type(4)));
typedef __bf16 bf16x8 __attribute__((ext_vector_type(8)));

#define MFMA(a, b, c) __builtin_amdgcn_mfma_f32_16x16x32_bf16((a), (b), (c), 0, 0, 0)

static constexpr int Bc = 4;      // batch
static constexpr int Sc = 2048;   // seq len
static constexpr int Hc = 16;     // heads
static constexpr int DHc = 64;    // head dim
static constexpr int Dc = 1024;   // model dim
static constexpr int Mc = Bc * Sc; // 8192 rows

// ---------------------------------------------------------------------------
// diagnostic: if ws_size is too small, stamp the output with 1000.0
// ---------------------------------------------------------------------------
__global__ void fill_diag(float* out, int n) {
    int i = blockIdx.x * 256 + threadIdx.x;
    if (i < n) out[i] = 1000.0f;
}

// ---------------------------------------------------------------------------
// 1024x1024 transpose + fp32->bf16 convert: out[n][k] = (bf16)in[k][n]
// ---------------------------------------------------------------------------
__global__ __launch_bounds__(256) void transpose1024(const float* __restrict__ in,
                                                     bf16* __restrict__ out) {
    __shared__ bf16 t[32][33];
    int x = blockIdx.x * 32 + threadIdx.x;
#pragma unroll
    for (int j = 0; j < 32; j += 8) {
        int y = blockIdx.y * 32 + threadIdx.y + j;
        t[threadIdx.y + j][threadIdx.x] = (bf16)in[y * 1024 + x];
    }
    __syncthreads();
    int x2 = blockIdx.y * 32 + threadIdx.x;
#pragma unroll
    for (int j = 0; j < 32; j += 8) {
        int y2 = blockIdx.x * 32 + threadIdx.y + j;
        out[y2 * 1024 + x2] = t[threadIdx.x][threadIdx.y + j];
    }
}

// ---------------------------------------------------------------------------
// C[M,N] = A[M,K] @ Wt[N,K]^T + bias[N]; A fp32 or bf16, Wt bf16,
// fp32 accum, TOUT out. 128x128 tile, 256 thr = 4 waves, 4x4 MFMA each.
// MODE 0: out row-major [M,N]; MODE 1: out [B,H,S,Dh]
// ---------------------------------------------------------------------------
template <int MODE, typename TA, typename TOUT>
__global__ __launch_bounds__(256) void gemm_bt(const TA* __restrict__ A,
                                               const bf16* __restrict__ Wt,
                                               const float* __restrict__ bias,
                                               TOUT* __restrict__ out,
                                               int M, int N, int K) {
    __shared__ alignas(16) bf16 As[128 * 32];
    __shared__ alignas(16) bf16 Bs[128 * 32];
    const int tid = threadIdx.x;
    const int wave = tid >> 6, lane = tid & 63;
    const int quad = lane >> 4, l16 = lane & 15;
    const int wr = (wave >> 1) * 64, wc = (wave & 1) * 64;
    const int row0 = blockIdx.y * 128, col0 = blockIdx.x * 128;

    f32x4 acc[4][4];
#pragma unroll
    for (int mi = 0; mi < 4; ++mi)
#pragma unroll
        for (int ni = 0; ni < 4; ++ni)
            acc[mi][ni] = (f32x4){0.f, 0.f, 0.f, 0.f};

    for (int k0 = 0; k0 < K; k0 += 32) {
        __syncthreads();
#pragma unroll
        for (int p = 0; p < 2; ++p) {
            int i = p * 256 + tid;
            int r = i >> 2, kb = (i & 3) * 8;
            if constexpr (std::is_same<TA, float>::value) {
                const float* s = &A[(size_t)(row0 + r) * K + k0 + kb];
                f32x4 x0 = *(const f32x4*)s;
                f32x4 x1 = *(const f32x4*)(s + 4);
                bf16x8 v;
#pragma unroll
                for (int j = 0; j < 4; ++j) {
                    v[j] = (bf16)x0[j];
                    v[j + 4] = (bf16)x1[j];
                }
                *(bf16x8*)&As[r * 32 + kb] = v;
            } else {
                *(uint4*)&As[r * 32 + kb] =
                    *(const uint4*)&A[(size_t)(row0 + r) * K + k0 + kb];
            }
            *(uint4*)&Bs[r * 32 + kb] =
                *(const uint4*)&Wt[(size_t)(col0 + r) * K + k0 + kb];
        }
        __syncthreads();
        bf16x8 af[4], bf_[4];
#pragma unroll
        for (int mi = 0; mi < 4; ++mi)
            af[mi] = *(const bf16x8*)&As[(wr + mi * 16 + l16) * 32 + quad * 8];
#pragma unroll
        for (int ni = 0; ni < 4; ++ni)
            bf_[ni] = *(const bf16x8*)&Bs[(wc + ni * 16 + l16) * 32 + quad * 8];
#pragma unroll
        for (int mi = 0; mi < 4; ++mi)
#pragma unroll
            for (int ni = 0; ni < 4; ++ni)
                acc[mi][ni] = MFMA(af[mi], bf_[ni], acc[mi][ni]);
    }

    // epilogue: C/D layout col=lane&15, row=quad*4+reg
#pragma unroll
    for (int mi = 0; mi < 4; ++mi) {
#pragma unroll
        for (int ni = 0; ni < 4; ++ni) {
            int col = col0 + wc + ni * 16 + l16;
            float bv = bias[col];
#pragma unroll
            for (int r = 0; r < 4; ++r) {
                int row = row0 + wr + mi * 16 + quad * 4 + r;
                float v = acc[mi][ni][r] + bv;
                size_t off;
                if (MODE == 0) {
                    off = (size_t)row * N + col;
                } else {
                    int b = row >> 11, s = row & (Sc - 1); // S = 2048
                    int h = col >> 6, dh = col & (DHc - 1);
                    off = (((size_t)(b * Hc + h) * Sc + s) << 6) + dh;
                }
                out[off] = (TOUT)v;
            }
        }
    }
}

// ---------------------------------------------------------------------------
// SIMPLE reference-style attention (correctness-first).
// One wave per query row. lane = head-dim element (Dh == 64 == wave size).
// Q,K,V: [B,H,S,Dh] bf16; mask: [B,S] int32; Ctx out: [B,S,H*Dh] bf16.
// grid: (S/4, B*H), block 256 = 4 waves.
// scale = 1/(Dh^2) = 1/4096, faithful to reference.
// ---------------------------------------------------------------------------
__global__ __launch_bounds__(256) void attn_simple(const bf16* __restrict__ Q,
                                                   const bf16* __restrict__ K,
                                                   const bf16* __restrict__ V,
                                                   const int* __restrict__ mask,
                                                   bf16* __restrict__ Ctx) {
    const int tid = threadIdx.x;
    const int wave = tid >> 6, lane = tid & 63;
    const int bh = blockIdx.y, b = bh >> 4, h = bh & 15;
    const int q = blockIdx.x * 4 + wave;
    const size_t base = (size_t)bh * Sc;

    const float qv = (float)Q[(base + q) * DHc + lane];
    float m = -3.0e38f, l = 0.f, o = 0.f;

    for (int j = 0; j <= q; ++j) {
        if (mask[b * Sc + j] == 0) continue;   // wave-uniform branch
        float kv = (float)K[(base + j) * DHc + lane];
        float dot = qv * kv;
#pragma unroll
        for (int off = 32; off >= 1; off >>= 1)
            dot += __shfl_xor(dot, off);
        float s = dot * (1.0f / 4096.0f);
        float mn = fmaxf(m, s);
        float sc = __expf(m - mn);
        float p  = __expf(s - mn);
        float vv = (float)V[(base + j) * DHc + lane];
        l = l * sc + p;
        o = o * sc + p * vv;
        m = mn;
    }
    Ctx[((size_t)b * Sc + q) * Dc + h * DHc + lane] = (bf16)(o / l);
}

// ---------------------------------------------------------------------------
extern "C" void kernel_launch(void* const* d_in, const int* in_sizes, int n_in,
                              void* d_out, int out_size, void* d_ws, size_t ws_size,
                              hipStream_t stream) {
    const float* query = (const float*)d_in[0];
    const float* key_i = (const float*)d_in[1];
    const float* value = (const float*)d_in[2];
    const int* mask    = (const int*)d_in[3];
    const float* W_q = (const float*)d_in[4];
    const float* b_q = (const float*)d_in[5];
    const float* W_k = (const float*)d_in[6];
    const float* b_k = (const float*)d_in[7];
    const float* W_v = (const float*)d_in[8];
    const float* b_v = (const float*)d_in[9];
    const float* W_o = (const float*)d_in[10];
    const float* b_o = (const float*)d_in[11];
    float* out = (float*)d_out;

    const size_t MB = 1024 * 1024;
    const size_t NEED = 72 * MB;
    if (ws_size < NEED) {
        // diagnostic fingerprint: absmax ~996-1000 => workspace too small
        fill_diag<<<(out_size + 255) / 256, 256, 0, stream>>>(out, out_size);
        return;
    }

    char* ws = (char*)d_ws;
    bf16* WtQ = (bf16*)(ws + 0 * MB);   // 1024x1024 bf16 = 2 MB each
    bf16* WtK = (bf16*)(ws + 2 * MB);
    bf16* WtV = (bf16*)(ws + 4 * MB);
    bf16* WtO = (bf16*)(ws + 6 * MB);
    bf16* Qb  = (bf16*)(ws + 8 * MB);   // [B,H,S,Dh] 16 MB
    bf16* Kb  = (bf16*)(ws + 24 * MB);  // [B,H,S,Dh]
    bf16* Vb  = (bf16*)(ws + 40 * MB);  // [B,H,S,Dh]
    bf16* Ctx = (bf16*)(ws + 56 * MB);  // [B,S,D]

    dim3 tb(32, 8), tg(32, 32);
    transpose1024<<<tg, tb, 0, stream>>>(W_q, WtQ);
    transpose1024<<<tg, tb, 0, stream>>>(W_k, WtK);
    transpose1024<<<tg, tb, 0, stream>>>(W_v, WtV);
    transpose1024<<<tg, tb, 0, stream>>>(W_o, WtO);

    dim3 gg(Dc / 128, Mc / 128); // (8, 64)
    gemm_bt<1, float, bf16><<<gg, 256, 0, stream>>>(query, WtQ, b_q, Qb, Mc, Dc, Dc);
    gemm_bt<1, float, bf16><<<gg, 256, 0, stream>>>(key_i, WtK, b_k, Kb, Mc, Dc, Dc);
    gemm_bt<1, float, bf16><<<gg, 256, 0, stream>>>(value, WtV, b_v, Vb, Mc, Dc, Dc);

    attn_simple<<<dim3(Sc / 4, Bc * Hc), 256, 0, stream>>>(Qb, Kb, Vb, mask, Ctx);

    gemm_bt<0, bf16, float><<<gg, 256, 0, stream>>>(Ctx, WtO, b_o, out, Mc, Dc, Dc);
}

// Round 4
// 612.563 us; speedup vs baseline: 16.5307x; 16.5307x over previous
//
#include <hip/hip_runtime.h>
#include <type_traits>

typedef __bf16 bf16;
typedef float f32x4 __attribute__((ext_vector_type(4)));
typedef __bf16 bf16x8 __attribute__((ext_vector_type(8)));

#define MFMA(a, b, c) __builtin_amdgcn_mfma_f32_16x16x32_bf16((a), (b), (c), 0, 0, 0)

static constexpr int Bc = 4;      // batch
static constexpr int Sc = 2048;   // seq len
static constexpr int Hc = 16;     // heads
static constexpr int DHc = 64;    // head dim
static constexpr int Dc = 1024;   // model dim
static constexpr int Mc = Bc * Sc; // 8192 rows

// ---------------------------------------------------------------------------
// diagnostic: if ws_size is too small, stamp the output with 1000.0
// ---------------------------------------------------------------------------
__global__ void fill_diag(float* out, int n) {
    int i = blockIdx.x * 256 + threadIdx.x;
    if (i < n) out[i] = 1000.0f;
}

// ---------------------------------------------------------------------------
// 1024x1024 transpose + fp32->bf16 convert: out[n][k] = (bf16)in[k][n]
// ---------------------------------------------------------------------------
__global__ __launch_bounds__(256) void transpose1024(const float* __restrict__ in,
                                                     bf16* __restrict__ out) {
    __shared__ bf16 t[32][33];
    int x = blockIdx.x * 32 + threadIdx.x;
#pragma unroll
    for (int j = 0; j < 32; j += 8) {
        int y = blockIdx.y * 32 + threadIdx.y + j;
        t[threadIdx.y + j][threadIdx.x] = (bf16)in[y * 1024 + x];
    }
    __syncthreads();
    int x2 = blockIdx.y * 32 + threadIdx.x;
#pragma unroll
    for (int j = 0; j < 32; j += 8) {
        int y2 = blockIdx.x * 32 + threadIdx.y + j;
        out[y2 * 1024 + x2] = t[threadIdx.x][threadIdx.y + j];
    }
}

// ---------------------------------------------------------------------------
// C[M,N] = A[M,K] @ Wt[N,K]^T + bias[N]; A fp32 or bf16, Wt bf16,
// fp32 accum, TOUT out. 128x128 tile, 256 thr = 4 waves, 4x4 MFMA each.
// MODE 0: out row-major [M,N]
// MODE 1: out [B,H,S,Dh]   (Q / K layout)
// MODE 2: out [B,H,Dh,S]   (V transposed layout)
// ---------------------------------------------------------------------------
template <int MODE, typename TA, typename TOUT>
__global__ __launch_bounds__(256) void gemm_bt(const TA* __restrict__ A,
                                               const bf16* __restrict__ Wt,
                                               const float* __restrict__ bias,
                                               TOUT* __restrict__ out,
                                               int M, int N, int K) {
    __shared__ alignas(16) bf16 As[128 * 32];
    __shared__ alignas(16) bf16 Bs[128 * 32];
    const int tid = threadIdx.x;
    const int wave = tid >> 6, lane = tid & 63;
    const int quad = lane >> 4, l16 = lane & 15;
    const int wr = (wave >> 1) * 64, wc = (wave & 1) * 64;
    const int row0 = blockIdx.y * 128, col0 = blockIdx.x * 128;

    f32x4 acc[4][4];
#pragma unroll
    for (int mi = 0; mi < 4; ++mi)
#pragma unroll
        for (int ni = 0; ni < 4; ++ni)
            acc[mi][ni] = (f32x4){0.f, 0.f, 0.f, 0.f};

    for (int k0 = 0; k0 < K; k0 += 32) {
        __syncthreads();
#pragma unroll
        for (int p = 0; p < 2; ++p) {
            int i = p * 256 + tid;
            int r = i >> 2, kb = (i & 3) * 8;
            if constexpr (std::is_same<TA, float>::value) {
                const float* s = &A[(size_t)(row0 + r) * K + k0 + kb];
                f32x4 x0 = *(const f32x4*)s;
                f32x4 x1 = *(const f32x4*)(s + 4);
                bf16x8 v;
#pragma unroll
                for (int j = 0; j < 4; ++j) {
                    v[j] = (bf16)x0[j];
                    v[j + 4] = (bf16)x1[j];
                }
                *(bf16x8*)&As[r * 32 + kb] = v;
            } else {
                *(uint4*)&As[r * 32 + kb] =
                    *(const uint4*)&A[(size_t)(row0 + r) * K + k0 + kb];
            }
            *(uint4*)&Bs[r * 32 + kb] =
                *(const uint4*)&Wt[(size_t)(col0 + r) * K + k0 + kb];
        }
        __syncthreads();
        bf16x8 af[4], bf_[4];
#pragma unroll
        for (int mi = 0; mi < 4; ++mi)
            af[mi] = *(const bf16x8*)&As[(wr + mi * 16 + l16) * 32 + quad * 8];
#pragma unroll
        for (int ni = 0; ni < 4; ++ni)
            bf_[ni] = *(const bf16x8*)&Bs[(wc + ni * 16 + l16) * 32 + quad * 8];
#pragma unroll
        for (int mi = 0; mi < 4; ++mi)
#pragma unroll
            for (int ni = 0; ni < 4; ++ni)
                acc[mi][ni] = MFMA(af[mi], bf_[ni], acc[mi][ni]);
    }

    // epilogue: C/D layout col=lane&15, row=quad*4+reg
#pragma unroll
    for (int mi = 0; mi < 4; ++mi) {
#pragma unroll
        for (int ni = 0; ni < 4; ++ni) {
            int col = col0 + wc + ni * 16 + l16;
            float bv = bias[col];
#pragma unroll
            for (int r = 0; r < 4; ++r) {
                int row = row0 + wr + mi * 16 + quad * 4 + r;
                float v = acc[mi][ni][r] + bv;
                size_t off;
                if (MODE == 0) {
                    off = (size_t)row * N + col;
                } else {
                    int b = row >> 11, s = row & (Sc - 1); // S = 2048
                    int h = col >> 6, dh = col & (DHc - 1);
                    if (MODE == 1)
                        off = (((size_t)(b * Hc + h) * Sc + s) << 6) + dh;
                    else
                        off = (((size_t)(b * Hc + h) * DHc + dh) << 11) + s;
                }
                out[off] = (TOUT)v;
            }
        }
    }
}

// ---------------------------------------------------------------------------
// Flash-style causal attention (MFMA).
// Q,K: [B,H,S,Dh] bf16; Vt: [B,H,Dh,S] bf16; mask: [B,S] int32
// Ctx out: [B,S,H*Dh] bf16
// grid: (S/64, B*H); block 256 = 4 waves; wave w owns q rows q0+w*16..+15.
// scale = 1/(Dh^2) = 1/4096, faithful to reference.
// ---------------------------------------------------------------------------
__global__ __launch_bounds__(256) void attn_fwd(const bf16* __restrict__ Q,
                                                const bf16* __restrict__ K,
                                                const bf16* __restrict__ Vt,
                                                const int* __restrict__ mask,
                                                bf16* __restrict__ Ctx) {
    __shared__ alignas(16) bf16 Ks[64 * 64];
    __shared__ alignas(16) bf16 Vs[64 * 64];   // Vs[dh][key]
    __shared__ alignas(16) bf16 Ps[4][16 * 64];
    __shared__ float msk[64];

    const int tid = threadIdx.x;
    const int wave = tid >> 6, lane = tid & 63;
    const int quad = lane >> 4, l16 = lane & 15;
    const int bh = blockIdx.y, b = bh >> 4, h = bh & 15;
    // heaviest q-tiles (most causal k-tiles) launch first
    const int qt = gridDim.x - 1 - blockIdx.x;
    const int q0 = qt * 64;
    const int qr = q0 + wave * 16;

    // Q fragments (A-operand): m = l16, k = quad*8+j (+32 for second chunk)
    bf16x8 aq[2];
    {
        const size_t qoff = ((size_t)bh * Sc + qr + l16) * DHc;
        aq[0] = *(const bf16x8*)&Q[qoff + quad * 8];
        aq[1] = *(const bf16x8*)&Q[qoff + 32 + quad * 8];
    }

    f32x4 accO[4];
#pragma unroll
    for (int oi = 0; oi < 4; ++oi) accO[oi] = (f32x4){0.f, 0.f, 0.f, 0.f};
    float m_run[4], l_run[4];
#pragma unroll
    for (int r = 0; r < 4; ++r) { m_run[r] = -1e30f; l_run[r] = 0.f; }

    const int nkt = qt + 1; // causal: k-tiles 0..qt
    for (int kt = 0; kt < nkt; ++kt) {
        const int kb = kt * 64;
        __syncthreads();
        // stage K tile [key][dh] and V tile [dh][key]
#pragma unroll
        for (int p = 0; p < 2; ++p) {
            int i = p * 256 + tid;
            int r = i >> 3, c8 = (i & 7) * 8;
            *(uint4*)&Ks[r * 64 + c8] =
                *(const uint4*)&K[((size_t)bh * Sc + kb + r) * DHc + c8];
            *(uint4*)&Vs[r * 64 + c8] =
                *(const uint4*)&Vt[((size_t)bh * DHc + r) * Sc + kb + c8];
        }
        if (tid < 64)
            msk[tid] = (mask[b * Sc + kb + tid] == 0) ? -1e30f : 0.0f;
        __syncthreads();

        // S = Q K^T : B-operand B[k=dh][n=key] = Ks[key][dh] rows
        f32x4 sc[4];
#pragma unroll
        for (int ni = 0; ni < 4; ++ni) {
            bf16x8 bk0 = *(const bf16x8*)&Ks[(ni * 16 + l16) * 64 + quad * 8];
            bf16x8 bk1 = *(const bf16x8*)&Ks[(ni * 16 + l16) * 64 + 32 + quad * 8];
            f32x4 z = {0.f, 0.f, 0.f, 0.f};
            z = MFMA(aq[0], bk0, z);
            z = MFMA(aq[1], bk1, z);
            sc[ni] = z;
        }

        // masked online softmax (rows live across 16 lanes of a quad-group)
        float p_[4][4]; // [ni][r]
        float alpha[4];
#pragma unroll
        for (int r = 0; r < 4; ++r) {
            int qg = qr + quad * 4 + r;
            float mx = -1e30f;
#pragma unroll
            for (int ni = 0; ni < 4; ++ni) {
                int kg = kb + ni * 16 + l16;
                float s = sc[ni][r] * (1.0f / 4096.0f) + msk[ni * 16 + l16];
                if (kg > qg) s = -1e30f;
                p_[ni][r] = s;
                mx = fmaxf(mx, s);
            }
#pragma unroll
            for (int off = 1; off < 16; off <<= 1)
                mx = fmaxf(mx, __shfl_xor(mx, off));
            float mnew = fmaxf(m_run[r], mx);
            float al = __expf(m_run[r] - mnew);
            float rs = 0.f;
#pragma unroll
            for (int ni = 0; ni < 4; ++ni) {
                float p = __expf(p_[ni][r] - mnew);
                p_[ni][r] = p;
                rs += p;
            }
#pragma unroll
            for (int off = 1; off < 16; off <<= 1)
                rs += __shfl_xor(rs, off);
            l_run[r] = l_run[r] * al + rs;
            m_run[r] = mnew;
            alpha[r] = al;
        }
#pragma unroll
        for (int oi = 0; oi < 4; ++oi) {
            f32x4 t = accO[oi];
#pragma unroll
            for (int r = 0; r < 4; ++r) t[r] *= alpha[r];
            accO[oi] = t;
        }

        // P: C-layout -> LDS -> A-operand layout (verified m120 pattern)
#pragma unroll
        for (int ni = 0; ni < 4; ++ni)
#pragma unroll
            for (int r = 0; r < 4; ++r)
                Ps[wave][(quad * 4 + r) * 64 + ni * 16 + l16] = (bf16)p_[ni][r];
        __syncthreads();

        // O += P V : A = Ps[q][key], B[k=key][n=dh] = Vs[dh][key] rows
#pragma unroll
        for (int kk = 0; kk < 2; ++kk) {
            bf16x8 ap = *(const bf16x8*)&Ps[wave][l16 * 64 + kk * 32 + quad * 8];
#pragma unroll
            for (int oi = 0; oi < 4; ++oi) {
                bf16x8 bv = *(const bf16x8*)&Vs[(oi * 16 + l16) * 64 + kk * 32 + quad * 8];
                accO[oi] = MFMA(ap, bv, accO[oi]);
            }
        }
    }

    // epilogue: Ctx[b][s][h*64+dh] = O / l
#pragma unroll
    for (int oi = 0; oi < 4; ++oi) {
#pragma unroll
        for (int r = 0; r < 4; ++r) {
            int s = qr + quad * 4 + r;
            int dh = oi * 16 + l16;
            float v = accO[oi][r] / l_run[r];
            Ctx[((size_t)b * Sc + s) * Dc + h * DHc + dh] = (bf16)v;
        }
    }
}

// ---------------------------------------------------------------------------
extern "C" void kernel_launch(void* const* d_in, const int* in_sizes, int n_in,
                              void* d_out, int out_size, void* d_ws, size_t ws_size,
                              hipStream_t stream) {
    const float* query = (const float*)d_in[0];
    const float* key_i = (const float*)d_in[1];
    const float* value = (const float*)d_in[2];
    const int* mask    = (const int*)d_in[3];
    const float* W_q = (const float*)d_in[4];
    const float* b_q = (const float*)d_in[5];
    const float* W_k = (const float*)d_in[6];
    const float* b_k = (const float*)d_in[7];
    const float* W_v = (const float*)d_in[8];
    const float* b_v = (const float*)d_in[9];
    const float* W_o = (const float*)d_in[10];
    const float* b_o = (const float*)d_in[11];
    float* out = (float*)d_out;

    const size_t MB = 1024 * 1024;
    const size_t NEED = 72 * MB;
    if (ws_size < NEED) {
        fill_diag<<<(out_size + 255) / 256, 256, 0, stream>>>(out, out_size);
        return;
    }

    char* ws = (char*)d_ws;
    bf16* WtQ = (bf16*)(ws + 0 * MB);   // 1024x1024 bf16 = 2 MB each
    bf16* WtK = (bf16*)(ws + 2 * MB);
    bf16* WtV = (bf16*)(ws + 4 * MB);
    bf16* WtO = (bf16*)(ws + 6 * MB);
    bf16* Qb  = (bf16*)(ws + 8 * MB);   // [B,H,S,Dh] 16 MB
    bf16* Kb  = (bf16*)(ws + 24 * MB);  // [B,H,S,Dh]
    bf16* Vtb = (bf16*)(ws + 40 * MB);  // [B,H,Dh,S]
    bf16* Ctx = (bf16*)(ws + 56 * MB);  // [B,S,D]

    dim3 tb(32, 8), tg(32, 32);
    transpose1024<<<tg, tb, 0, stream>>>(W_q, WtQ);
    transpose1024<<<tg, tb, 0, stream>>>(W_k, WtK);
    transpose1024<<<tg, tb, 0, stream>>>(W_v, WtV);
    transpose1024<<<tg, tb, 0, stream>>>(W_o, WtO);

    dim3 gg(Dc / 128, Mc / 128); // (8, 64)
    gemm_bt<1, float, bf16><<<gg, 256, 0, stream>>>(query, WtQ, b_q, Qb, Mc, Dc, Dc);
    gemm_bt<1, float, bf16><<<gg, 256, 0, stream>>>(key_i, WtK, b_k, Kb, Mc, Dc, Dc);
    gemm_bt<2, float, bf16><<<gg, 256, 0, stream>>>(value, WtV, b_v, Vtb, Mc, Dc, Dc);

    attn_fwd<<<dim3(Sc / 64, Bc * Hc), 256, 0, stream>>>(Qb, Kb, Vtb, mask, Ctx);

    gemm_bt<0, bf16, float><<<gg, 256, 0, stream>>>(Ctx, WtO, b_o, out, Mc, Dc, Dc);
}

// Round 5
// 436.059 us; speedup vs baseline: 23.2218x; 1.4048x over previous
//
#include <hip/hip_runtime.h>
#include <type_traits>

typedef __bf16 bf16;
typedef float f32x4 __attribute__((ext_vector_type(4)));
typedef __bf16 bf16x8 __attribute__((ext_vector_type(8)));

#define MFMA(a, b, c) __builtin_amdgcn_mfma_f32_16x16x32_bf16((a), (b), (c), 0, 0, 0)

static constexpr int Bc = 4;      // batch
static constexpr int Sc = 2048;   // seq len
static constexpr int Hc = 16;     // heads
static constexpr int DHc = 64;    // head dim
static constexpr int Dc = 1024;   // model dim
static constexpr int Mc = Bc * Sc; // 8192 rows

// ---------------------------------------------------------------------------
// diagnostic: if ws_size is too small, stamp the output with 1000.0
// ---------------------------------------------------------------------------
__global__ void fill_diag(float* out, int n) {
    int i = blockIdx.x * 256 + threadIdx.x;
    if (i < n) out[i] = 1000.0f;
}

// ---------------------------------------------------------------------------
// 1024x1024 transpose + fp32->bf16 convert: out[n][k] = (bf16)in[k][n]
// ---------------------------------------------------------------------------
__global__ __launch_bounds__(256) void transpose1024(const float* __restrict__ in,
                                                     bf16* __restrict__ out) {
    __shared__ bf16 t[32][33];
    int x = blockIdx.x * 32 + threadIdx.x;
#pragma unroll
    for (int j = 0; j < 32; j += 8) {
        int y = blockIdx.y * 32 + threadIdx.y + j;
        t[threadIdx.y + j][threadIdx.x] = (bf16)in[y * 1024 + x];
    }
    __syncthreads();
    int x2 = blockIdx.y * 32 + threadIdx.x;
#pragma unroll
    for (int j = 0; j < 32; j += 8) {
        int y2 = blockIdx.x * 32 + threadIdx.y + j;
        out[y2 * 1024 + x2] = t[threadIdx.x][threadIdx.y + j];
    }
}

// ---------------------------------------------------------------------------
// C[M,N] = A[M,K] @ Wt[N,K]^T + bias[N]; A fp32 or bf16, Wt bf16,
// fp32 accum, TOUT out. 128x128 tile, 256 thr = 4 waves, 4x4 MFMA each.
// MODE 0: out row-major [M,N]
// MODE 1: out [B,H,S,Dh]   (Q / K layout)
// MODE 2: out [B,H,Dh,S]   (V transposed layout)
// ---------------------------------------------------------------------------
template <int MODE, typename TA, typename TOUT>
__global__ __launch_bounds__(256) void gemm_bt(const TA* __restrict__ A,
                                               const bf16* __restrict__ Wt,
                                               const float* __restrict__ bias,
                                               TOUT* __restrict__ out,
                                               int M, int N, int K) {
    __shared__ alignas(16) bf16 As[128 * 32];
    __shared__ alignas(16) bf16 Bs[128 * 32];
    const int tid = threadIdx.x;
    const int wave = tid >> 6, lane = tid & 63;
    const int quad = lane >> 4, l16 = lane & 15;
    const int wr = (wave >> 1) * 64, wc = (wave & 1) * 64;
    const int row0 = blockIdx.y * 128, col0 = blockIdx.x * 128;

    f32x4 acc[4][4];
#pragma unroll
    for (int mi = 0; mi < 4; ++mi)
#pragma unroll
        for (int ni = 0; ni < 4; ++ni)
            acc[mi][ni] = (f32x4){0.f, 0.f, 0.f, 0.f};

    for (int k0 = 0; k0 < K; k0 += 32) {
        __syncthreads();
#pragma unroll
        for (int p = 0; p < 2; ++p) {
            int i = p * 256 + tid;
            int r = i >> 2, kb = (i & 3) * 8;
            if constexpr (std::is_same<TA, float>::value) {
                const float* s = &A[(size_t)(row0 + r) * K + k0 + kb];
                f32x4 x0 = *(const f32x4*)s;
                f32x4 x1 = *(const f32x4*)(s + 4);
                bf16x8 v;
#pragma unroll
                for (int j = 0; j < 4; ++j) {
                    v[j] = (bf16)x0[j];
                    v[j + 4] = (bf16)x1[j];
                }
                *(bf16x8*)&As[r * 32 + kb] = v;
            } else {
                *(uint4*)&As[r * 32 + kb] =
                    *(const uint4*)&A[(size_t)(row0 + r) * K + k0 + kb];
            }
            *(uint4*)&Bs[r * 32 + kb] =
                *(const uint4*)&Wt[(size_t)(col0 + r) * K + k0 + kb];
        }
        __syncthreads();
        bf16x8 af[4], bf_[4];
#pragma unroll
        for (int mi = 0; mi < 4; ++mi)
            af[mi] = *(const bf16x8*)&As[(wr + mi * 16 + l16) * 32 + quad * 8];
#pragma unroll
        for (int ni = 0; ni < 4; ++ni)
            bf_[ni] = *(const bf16x8*)&Bs[(wc + ni * 16 + l16) * 32 + quad * 8];
#pragma unroll
        for (int mi = 0; mi < 4; ++mi)
#pragma unroll
            for (int ni = 0; ni < 4; ++ni)
                acc[mi][ni] = MFMA(af[mi], bf_[ni], acc[mi][ni]);
    }

    // epilogue: C/D layout col=lane&15, row=quad*4+reg
#pragma unroll
    for (int mi = 0; mi < 4; ++mi) {
#pragma unroll
        for (int ni = 0; ni < 4; ++ni) {
            int col = col0 + wc + ni * 16 + l16;
            float bv = bias[col];
#pragma unroll
            for (int r = 0; r < 4; ++r) {
                int row = row0 + wr + mi * 16 + quad * 4 + r;
                float v = acc[mi][ni][r] + bv;
                size_t off;
                if (MODE == 0) {
                    off = (size_t)row * N + col;
                } else {
                    int b = row >> 11, s = row & (Sc - 1); // S = 2048
                    int h = col >> 6, dh = col & (DHc - 1);
                    if (MODE == 1)
                        off = (((size_t)(b * Hc + h) * Sc + s) << 6) + dh;
                    else
                        off = (((size_t)(b * Hc + h) * DHc + dh) << 11) + s;
                }
                out[off] = (TOUT)v;
            }
        }
    }
}

// ---------------------------------------------------------------------------
// Flash-style causal attention (MFMA), v2.
// Q,K: [B,H,S,Dh] bf16; Vt: [B,H,Dh,S] bf16; mask: [B,S] int32
// Ctx out: [B,S,H*Dh] bf16
// grid: (S/128, B*H); block 256 = 4 waves; wave w owns 32 q-rows (2 m-tiles).
// scale = 1/(Dh^2) = 1/4096  =>  |s| << 1, so exp() cannot overflow and the
// softmax shift m can be fixed at 0: no cross-lane max, no rescale chain.
// LDS rows padded to 72 bf16 (144 B) so b128 frag reads hit the 8-cycle
// wave64 floor (unpadded 64-el rows put 16 lanes on one 4-bank group = 2x).
// ---------------------------------------------------------------------------
static constexpr int LP = 72; // padded LDS row stride (elements)

__global__ __launch_bounds__(256, 4) void attn_fwd(const bf16* __restrict__ Q,
                                                   const bf16* __restrict__ K,
                                                   const bf16* __restrict__ Vt,
                                                   const int* __restrict__ mask,
                                                   bf16* __restrict__ Ctx) {
    __shared__ alignas(16) bf16 Ks[64 * LP];
    __shared__ alignas(16) bf16 Vs[64 * LP];      // Vs[dh][key]
    __shared__ alignas(16) bf16 Ps[4][32 * LP];   // per-wave P (32 q-rows)
    __shared__ float msk[64];

    const int tid = threadIdx.x;
    const int wave = tid >> 6, lane = tid & 63;
    const int quad = lane >> 4, l16 = lane & 15;
    const int bh = blockIdx.y, b = bh >> 4, h = bh & 15;
    // heaviest q-tiles (most causal k-tiles) launch first
    const int qt = gridDim.x - 1 - blockIdx.x;
    const int q0 = qt * 128;
    const int qr0 = q0 + wave * 32;        // m-tile 0 rows
    const int qr1 = qr0 + 16;              // m-tile 1 rows
    const int qmax = qr0 + 31;             // wave's last q row

    // Q fragments (A-operand): m = l16, k = quad*8+j ; [mt][k-chunk]
    bf16x8 aq[2][2];
#pragma unroll
    for (int mt = 0; mt < 2; ++mt) {
        const size_t qoff = ((size_t)bh * Sc + (mt ? qr1 : qr0) + l16) * DHc;
        aq[mt][0] = *(const bf16x8*)&Q[qoff + quad * 8];
        aq[mt][1] = *(const bf16x8*)&Q[qoff + 32 + quad * 8];
    }

    f32x4 accO[2][4];
#pragma unroll
    for (int mt = 0; mt < 2; ++mt)
#pragma unroll
        for (int oi = 0; oi < 4; ++oi) accO[mt][oi] = (f32x4){0.f, 0.f, 0.f, 0.f};
    float l_part[2][4] = {};               // per-lane partial row sums

    const int nkt = 2 * qt + 2;            // causal: k-tiles 0..(2qt+1)
    for (int kt = 0; kt < nkt; ++kt) {
        const int kb = kt * 64;
        __syncthreads();                   // prior PV reads done before restage
#pragma unroll
        for (int p = 0; p < 2; ++p) {
            int i = p * 256 + tid;
            int r = i >> 3, c8 = (i & 7) * 8;
            *(uint4*)&Ks[r * LP + c8] =
                *(const uint4*)&K[((size_t)bh * Sc + kb + r) * DHc + c8];
            *(uint4*)&Vs[r * LP + c8] =
                *(const uint4*)&Vt[((size_t)bh * DHc + r) * Sc + kb + c8];
        }
        if (tid < 64)
            msk[tid] = (mask[b * Sc + kb + tid] == 0) ? -1e30f : 0.0f;
        __syncthreads();

        if (kb > qmax) continue;           // wave-uniform: tile fully future

        // S = Q K^T  (B-frags shared across both m-tiles)
        f32x4 sc[2][4];
#pragma unroll
        for (int ni = 0; ni < 4; ++ni) {
            bf16x8 bk0 = *(const bf16x8*)&Ks[(ni * 16 + l16) * LP + quad * 8];
            bf16x8 bk1 = *(const bf16x8*)&Ks[(ni * 16 + l16) * LP + 32 + quad * 8];
#pragma unroll
            for (int mt = 0; mt < 2; ++mt) {
                f32x4 z = {0.f, 0.f, 0.f, 0.f};
                z = MFMA(aq[mt][0], bk0, z);
                z = MFMA(aq[mt][1], bk1, z);
                sc[mt][ni] = z;
            }
        }

        // softmax numerator with fixed shift m=0; P -> per-wave LDS
#pragma unroll
        for (int mt = 0; mt < 2; ++mt) {
            const int qbase = (mt ? qr1 : qr0) + quad * 4;
#pragma unroll
            for (int ni = 0; ni < 4; ++ni) {
                const int kg = kb + ni * 16 + l16;
                const float mk = msk[ni * 16 + l16];
#pragma unroll
                for (int r = 0; r < 4; ++r) {
                    float s = sc[mt][ni][r] * (1.0f / 4096.0f) + mk;
                    s = (kg > qbase + r) ? -1e30f : s;
                    float p = __expf(s);
                    l_part[mt][r] += p;
                    Ps[wave][(mt * 16 + quad * 4 + r) * LP + ni * 16 + l16] = (bf16)p;
                }
            }
        }
        // no barrier needed: Ps[wave] is single-wave private (lgkmcnt order)

        // O += P V  (B-frags shared across both m-tiles)
#pragma unroll
        for (int kk = 0; kk < 2; ++kk) {
            bf16x8 ap0 = *(const bf16x8*)&Ps[wave][(l16) * LP + kk * 32 + quad * 8];
            bf16x8 ap1 = *(const bf16x8*)&Ps[wave][(16 + l16) * LP + kk * 32 + quad * 8];
#pragma unroll
            for (int oi = 0; oi < 4; ++oi) {
                bf16x8 bv = *(const bf16x8*)&Vs[(oi * 16 + l16) * LP + kk * 32 + quad * 8];
                accO[0][oi] = MFMA(ap0, bv, accO[0][oi]);
                accO[1][oi] = MFMA(ap1, bv, accO[1][oi]);
            }
        }
    }

    // epilogue: reduce l across the 16 column-lanes (within quad-group), divide
#pragma unroll
    for (int mt = 0; mt < 2; ++mt) {
#pragma unroll
        for (int r = 0; r < 4; ++r) {
            float l = l_part[mt][r];
#pragma unroll
            for (int off = 1; off < 16; off <<= 1)
                l += __shfl_xor(l, off);
            l_part[mt][r] = l;
        }
#pragma unroll
        for (int oi = 0; oi < 4; ++oi) {
#pragma unroll
            for (int r = 0; r < 4; ++r) {
                int s = (mt ? qr1 : qr0) + quad * 4 + r;
                int dh = oi * 16 + l16;
                float v = accO[mt][oi][r] / l_part[mt][r];
                Ctx[((size_t)b * Sc + s) * Dc + h * DHc + dh] = (bf16)v;
            }
        }
    }
}

// ---------------------------------------------------------------------------
extern "C" void kernel_launch(void* const* d_in, const int* in_sizes, int n_in,
                              void* d_out, int out_size, void* d_ws, size_t ws_size,
                              hipStream_t stream) {
    const float* query = (const float*)d_in[0];
    const float* key_i = (const float*)d_in[1];
    const float* value = (const float*)d_in[2];
    const int* mask    = (const int*)d_in[3];
    const float* W_q = (const float*)d_in[4];
    const float* b_q = (const float*)d_in[5];
    const float* W_k = (const float*)d_in[6];
    const float* b_k = (const float*)d_in[7];
    const float* W_v = (const float*)d_in[8];
    const float* b_v = (const float*)d_in[9];
    const float* W_o = (const float*)d_in[10];
    const float* b_o = (const float*)d_in[11];
    float* out = (float*)d_out;

    const size_t MB = 1024 * 1024;
    const size_t NEED = 72 * MB;
    if (ws_size < NEED) {
        fill_diag<<<(out_size + 255) / 256, 256, 0, stream>>>(out, out_size);
        return;
    }

    char* ws = (char*)d_ws;
    bf16* WtQ = (bf16*)(ws + 0 * MB);   // 1024x1024 bf16 = 2 MB each
    bf16* WtK = (bf16*)(ws + 2 * MB);
    bf16* WtV = (bf16*)(ws + 4 * MB);
    bf16* WtO = (bf16*)(ws + 6 * MB);
    bf16* Qb  = (bf16*)(ws + 8 * MB);   // [B,H,S,Dh] 16 MB
    bf16* Kb  = (bf16*)(ws + 24 * MB);  // [B,H,S,Dh]
    bf16* Vtb = (bf16*)(ws + 40 * MB);  // [B,H,Dh,S]
    bf16* Ctx = (bf16*)(ws + 56 * MB);  // [B,S,D]

    dim3 tb(32, 8), tg(32, 32);
    transpose1024<<<tg, tb, 0, stream>>>(W_q, WtQ);
    transpose1024<<<tg, tb, 0, stream>>>(W_k, WtK);
    transpose1024<<<tg, tb, 0, stream>>>(W_v, WtV);
    transpose1024<<<tg, tb, 0, stream>>>(W_o, WtO);

    dim3 gg(Dc / 128, Mc / 128); // (8, 64)
    gemm_bt<1, float, bf16><<<gg, 256, 0, stream>>>(query, WtQ, b_q, Qb, Mc, Dc, Dc);
    gemm_bt<1, float, bf16><<<gg, 256, 0, stream>>>(key_i, WtK, b_k, Kb, Mc, Dc, Dc);
    gemm_bt<2, float, bf16><<<gg, 256, 0, stream>>>(value, WtV, b_v, Vtb, Mc, Dc, Dc);

    attn_fwd<<<dim3(Sc / 128, Bc * Hc), 256, 0, stream>>>(Qb, Kb, Vtb, mask, Ctx);

    gemm_bt<0, bf16, float><<<gg, 256, 0, stream>>>(Ctx, WtO, b_o, out, Mc, Dc, Dc);
}

// Round 6
// 417.789 us; speedup vs baseline: 24.2373x; 1.0437x over previous
//
#include <hip/hip_runtime.h>

typedef __bf16 bf16;
typedef unsigned int u32;
typedef float f32x4 __attribute__((ext_vector_type(4)));
typedef __bf16 bf16x4 __attribute__((ext_vector_type(4)));
typedef __bf16 bf16x8 __attribute__((ext_vector_type(8)));

#define MFMA(a, b, c) __builtin_amdgcn_mfma_f32_16x16x32_bf16((a), (b), (c), 0, 0, 0)

static constexpr int Bc = 4;      // batch
static constexpr int Sc = 2048;   // seq len
static constexpr int Hc = 16;     // heads
static constexpr int DHc = 64;    // head dim
static constexpr int Dc = 1024;   // model dim
static constexpr int Mc = Bc * Sc; // 8192 rows

// async 16B/lane global->LDS. lp must be wave-uniform; lane i lands at lp+16*i.
__device__ __forceinline__ void load_lds16(const bf16* gp, bf16* lp) {
    __builtin_amdgcn_global_load_lds(
        reinterpret_cast<const __attribute__((address_space(1))) u32*>(
            reinterpret_cast<uintptr_t>(gp)),
        reinterpret_cast<__attribute__((address_space(3))) u32*>(
            static_cast<u32>(reinterpret_cast<uintptr_t>(lp))),
        16, 0, 0);
}

// ---------------------------------------------------------------------------
__global__ void fill_diag(float* out, int n) {
    int i = blockIdx.x * 256 + threadIdx.x;
    if (i < n) out[i] = 1000.0f;
}

// ---------------------------------------------------------------------------
// fp32 -> bf16 bulk convert (8 elems/thread)
// ---------------------------------------------------------------------------
__global__ __launch_bounds__(256) void cvt_bf16(const float* __restrict__ in,
                                                bf16* __restrict__ out, int n) {
    int i = (blockIdx.x * 256 + threadIdx.x) * 8;
    if (i < n) {
        f32x4 a = *(const f32x4*)&in[i];
        f32x4 b = *(const f32x4*)&in[i + 4];
        bf16x8 v;
#pragma unroll
        for (int j = 0; j < 4; ++j) { v[j] = (bf16)a[j]; v[j + 4] = (bf16)b[j]; }
        *(bf16x8*)&out[i] = v;
    }
}

// ---------------------------------------------------------------------------
// 1024x1024 transpose + fp32->bf16: out[n][k] = (bf16)in[k][n]
// ---------------------------------------------------------------------------
__global__ __launch_bounds__(256) void transpose1024(const float* __restrict__ in,
                                                     bf16* __restrict__ out) {
    __shared__ bf16 t[32][33];
    int x = blockIdx.x * 32 + threadIdx.x;
#pragma unroll
    for (int j = 0; j < 32; j += 8) {
        int y = blockIdx.y * 32 + threadIdx.y + j;
        t[threadIdx.y + j][threadIdx.x] = (bf16)in[y * 1024 + x];
    }
    __syncthreads();
    int x2 = blockIdx.y * 32 + threadIdx.x;
#pragma unroll
    for (int j = 0; j < 32; j += 8) {
        int y2 = blockIdx.x * 32 + threadIdx.y + j;
        out[y2 * 1024 + x2] = t[threadIdx.x][threadIdx.y + j];
    }
}

// ---------------------------------------------------------------------------
// C[M,N] = A[M,K] @ Wt[N,K]^T + bias[N]; bf16 in, fp32 accum, TOUT out.
// m97 pattern: global_load_lds width-16 staging, 128x128 tile, BK=32,
// 256 thr = 4 waves, 4x4 MFMA per wave.
// MODE 0: out row-major [M,N]; MODE 1: [B,H,S,Dh]; MODE 2: [B,H,Dh,S]
// ---------------------------------------------------------------------------
template <int MODE, typename TOUT>
__global__ __launch_bounds__(256) void gemm_bt(const bf16* __restrict__ A,
                                               const bf16* __restrict__ Wt,
                                               const float* __restrict__ bias,
                                               TOUT* __restrict__ out,
                                               int M, int N, int K) {
    __shared__ alignas(16) bf16 As[128 * 32];
    __shared__ alignas(16) bf16 Bs[128 * 32];
    const int tid = threadIdx.x;
    const int wave = tid >> 6, lane = tid & 63;
    const int quad = lane >> 4, l16 = lane & 15;
    const int wr = (wave >> 1) * 64, wc = (wave & 1) * 64;
    const int row0 = blockIdx.y * 128, col0 = blockIdx.x * 128;

    // staging addresses: wave covers rows [wave*32, wave*32+32), lane i ->
    // row wave*32 + p*16 + i/4, k-chunk (i&3)*8  (16B per lane, contiguous LDS)
    const int sr = wave * 32 + (lane >> 2);
    const int sk = (lane & 3) * 8;
    const bf16* gA = &A[(size_t)(row0 + sr) * K + sk];
    const bf16* gB = &Wt[(size_t)(col0 + sr) * K + sk];
    bf16* lA = &As[wave * 32 * 32];
    bf16* lB = &Bs[wave * 32 * 32];

    f32x4 acc[4][4];
#pragma unroll
    for (int mi = 0; mi < 4; ++mi)
#pragma unroll
        for (int ni = 0; ni < 4; ++ni)
            acc[mi][ni] = (f32x4){0.f, 0.f, 0.f, 0.f};

    for (int k0 = 0; k0 < K; k0 += 32) {
        __syncthreads();
        load_lds16(gA + k0, lA);
        load_lds16(gA + k0 + 16 * K, lA + 16 * 32);
        load_lds16(gB + k0, lB);
        load_lds16(gB + k0 + 16 * K, lB + 16 * 32);
        __syncthreads();   // drains vmcnt before LDS reads

        bf16x8 af[4], bf_[4];
#pragma unroll
        for (int mi = 0; mi < 4; ++mi)
            af[mi] = *(const bf16x8*)&As[(wr + mi * 16 + l16) * 32 + quad * 8];
#pragma unroll
        for (int ni = 0; ni < 4; ++ni)
            bf_[ni] = *(const bf16x8*)&Bs[(wc + ni * 16 + l16) * 32 + quad * 8];
#pragma unroll
        for (int mi = 0; mi < 4; ++mi)
#pragma unroll
            for (int ni = 0; ni < 4; ++ni)
                acc[mi][ni] = MFMA(af[mi], bf_[ni], acc[mi][ni]);
    }

    // epilogue: C/D layout col=lane&15, row=quad*4+reg
#pragma unroll
    for (int mi = 0; mi < 4; ++mi) {
#pragma unroll
        for (int ni = 0; ni < 4; ++ni) {
            int col = col0 + wc + ni * 16 + l16;
            float bv = bias[col];
#pragma unroll
            for (int r = 0; r < 4; ++r) {
                int row = row0 + wr + mi * 16 + quad * 4 + r;
                float v = acc[mi][ni][r] + bv;
                size_t off;
                if (MODE == 0) {
                    off = (size_t)row * N + col;
                } else {
                    int b = row >> 11, s = row & (Sc - 1); // S = 2048
                    int h = col >> 6, dh = col & (DHc - 1);
                    if (MODE == 1)
                        off = (((size_t)(b * Hc + h) * Sc + s) << 6) + dh;
                    else
                        off = (((size_t)(b * Hc + h) * DHc + dh) << 11) + s;
                }
                out[off] = (TOUT)v;
            }
        }
    }
}

// ---------------------------------------------------------------------------
// Flash-style causal attention (MFMA), v3: S^T formulation.
// S^T = K*Q^T (operand-swapped MFMA, same fragments) puts KEY in the C-layout
// register direction -> P packs into ds_write_b64 (was 32x ds_write_b16), the
// pad mask folds into one FMA via broadcast f32x4, and l is a pure per-lane
// partial (cross-lane only in epilogue).
// Q,K: [B,H,S,Dh] bf16; Vt: [B,H,Dh,S] bf16; mask: [B,S] int32
// grid: (S/128, B*H); block 256 = 4 waves; wave owns 32 q-rows (2 m-tiles).
// scale = 1/Dh^2 = 1/4096 => |s| << 1, softmax shift fixed at 0.
// ---------------------------------------------------------------------------
static constexpr int LP = 72; // padded LDS row stride (elements)

__global__ __launch_bounds__(256, 4) void attn_fwd(const bf16* __restrict__ Q,
                                                   const bf16* __restrict__ K,
                                                   const bf16* __restrict__ Vt,
                                                   const int* __restrict__ mask,
                                                   bf16* __restrict__ Ctx) {
    __shared__ alignas(16) bf16 Ks[64 * LP];
    __shared__ alignas(16) bf16 Vs[64 * LP];      // Vs[dh][key]
    __shared__ alignas(16) bf16 Ps[4][32 * LP];   // per-wave P[q][key]
    __shared__ alignas(16) float msk[64];

    const int tid = threadIdx.x;
    const int wave = tid >> 6, lane = tid & 63;
    const int quad = lane >> 4, l16 = lane & 15;
    const int bh = blockIdx.y, b = bh >> 4, h = bh & 15;
    const int qt = gridDim.x - 1 - blockIdx.x;   // heaviest first
    const int q0 = qt * 128;
    const int qr0 = q0 + wave * 32;
    const int qmax = qr0 + 31;

    // Q fragments (B-operand of S^T): n=q=l16, k=dh=quad*8+j ; [mt][chunk]
    bf16x8 bq[2][2];
#pragma unroll
    for (int mt = 0; mt < 2; ++mt) {
        const size_t qoff = ((size_t)bh * Sc + qr0 + mt * 16 + l16) * DHc;
        bq[mt][0] = *(const bf16x8*)&Q[qoff + quad * 8];
        bq[mt][1] = *(const bf16x8*)&Q[qoff + 32 + quad * 8];
    }

    f32x4 accO[2][4];
#pragma unroll
    for (int mt = 0; mt < 2; ++mt)
#pragma unroll
        for (int oi = 0; oi < 4; ++oi) accO[mt][oi] = (f32x4){0.f, 0.f, 0.f, 0.f};
    float l_part[2] = {0.f, 0.f};                // per-lane partial for q=l16

    const int nkt = 2 * qt + 2;                  // causal: k-tiles 0..(2qt+1)
    for (int kt = 0; kt < nkt; ++kt) {
        const int kb = kt * 64;
        __syncthreads();
#pragma unroll
        for (int p = 0; p < 2; ++p) {
            int i = p * 256 + tid;
            int r = i >> 3, c8 = (i & 7) * 8;
            *(uint4*)&Ks[r * LP + c8] =
                *(const uint4*)&K[((size_t)bh * Sc + kb + r) * DHc + c8];
            *(uint4*)&Vs[r * LP + c8] =
                *(const uint4*)&Vt[((size_t)bh * DHc + r) * Sc + kb + c8];
        }
        if (tid < 64)
            msk[tid] = (mask[b * Sc + kb + tid] == 0) ? -1e30f : 0.0f;
        __syncthreads();

        if (kb > qmax) continue;                 // wave-uniform skip

        // S^T = K Q^T : A-frag = K rows (m=key), B-frag = bq (n=q)
        f32x4 st[2][4];                          // [mt][kti]
#pragma unroll
        for (int kti = 0; kti < 4; ++kti) {
            bf16x8 ak0 = *(const bf16x8*)&Ks[(kti * 16 + l16) * LP + quad * 8];
            bf16x8 ak1 = *(const bf16x8*)&Ks[(kti * 16 + l16) * LP + 32 + quad * 8];
#pragma unroll
            for (int mt = 0; mt < 2; ++mt) {
                f32x4 z = {0.f, 0.f, 0.f, 0.f};
                z = MFMA(ak0, bq[mt][0], z);
                z = MFMA(ak1, bq[mt][1], z);
                st[mt][kti] = z;
            }
        }

        // softmax numerator (shift=0); packed P store: key contiguous in regs
#pragma unroll
        for (int mt = 0; mt < 2; ++mt) {
#pragma unroll
            for (int kti = 0; kti < 4; ++kti) {
                const f32x4 mkv = *(const f32x4*)&msk[kti * 16 + quad * 4];
                const int cbase = kb + kti * 16 + quad * 4 - (qr0 + mt * 16);
                bf16x4 pv;
#pragma unroll
                for (int r = 0; r < 4; ++r) {
                    float s = st[mt][kti][r] * (1.0f / 4096.0f) + mkv[r];
                    s = (cbase + r > l16) ? -1e30f : s;   // causal: kg > qg
                    float p = __expf(s);
                    l_part[mt] += p;
                    pv[r] = (bf16)p;
                }
                *(bf16x4*)&Ps[wave][(mt * 16 + l16) * LP + kti * 16 + quad * 4] = pv;
            }
        }
        // Ps[wave] is wave-private; per-wave DS ordering suffices (no barrier)

        // O += P V : A = Ps rows (m=q), B = Vs rows (n=dh)
#pragma unroll
        for (int kk = 0; kk < 2; ++kk) {
            bf16x8 ap0 = *(const bf16x8*)&Ps[wave][(l16) * LP + kk * 32 + quad * 8];
            bf16x8 ap1 = *(const bf16x8*)&Ps[wave][(16 + l16) * LP + kk * 32 + quad * 8];
#pragma unroll
            for (int oi = 0; oi < 4; ++oi) {
                bf16x8 bv = *(const bf16x8*)&Vs[(oi * 16 + l16) * LP + kk * 32 + quad * 8];
                accO[0][oi] = MFMA(ap0, bv, accO[0][oi]);
                accO[1][oi] = MFMA(ap1, bv, accO[1][oi]);
            }
        }
    }

    // epilogue: finish l (sum over quads), redistribute to C-layout rows, store
    float lv[2][4];
#pragma unroll
    for (int mt = 0; mt < 2; ++mt) {
        float l = l_part[mt];
        l += __shfl_xor(l, 16);
        l += __shfl_xor(l, 32);                  // lane now holds l for q=l16
#pragma unroll
        for (int r = 0; r < 4; ++r)
            lv[mt][r] = __shfl(l, quad * 4 + r); // l for q=quad*4+r
    }
#pragma unroll
    for (int mt = 0; mt < 2; ++mt)
#pragma unroll
        for (int oi = 0; oi < 4; ++oi)
#pragma unroll
            for (int r = 0; r < 4; ++r) {
                int s = qr0 + mt * 16 + quad * 4 + r;
                int dh = oi * 16 + l16;
                float v = accO[mt][oi][r] / lv[mt][r];
                Ctx[((size_t)b * Sc + s) * Dc + h * DHc + dh] = (bf16)v;
            }
}

// ---------------------------------------------------------------------------
extern "C" void kernel_launch(void* const* d_in, const int* in_sizes, int n_in,
                              void* d_out, int out_size, void* d_ws, size_t ws_size,
                              hipStream_t stream) {
    const float* query = (const float*)d_in[0];
    const float* key_i = (const float*)d_in[1];
    const float* value = (const float*)d_in[2];
    const int* mask    = (const int*)d_in[3];
    const float* W_q = (const float*)d_in[4];
    const float* b_q = (const float*)d_in[5];
    const float* W_k = (const float*)d_in[6];
    const float* b_k = (const float*)d_in[7];
    const float* W_v = (const float*)d_in[8];
    const float* b_v = (const float*)d_in[9];
    const float* W_o = (const float*)d_in[10];
    const float* b_o = (const float*)d_in[11];
    float* out = (float*)d_out;

    const size_t MB = 1024 * 1024;
    const size_t NEED = 72 * MB;
    if (ws_size < NEED) {
        fill_diag<<<(out_size + 255) / 256, 256, 0, stream>>>(out, out_size);
        return;
    }

    char* ws = (char*)d_ws;
    bf16* WtQ = (bf16*)(ws + 0 * MB);   // 2 MB each
    bf16* WtK = (bf16*)(ws + 2 * MB);
    bf16* WtV = (bf16*)(ws + 4 * MB);
    bf16* WtO = (bf16*)(ws + 6 * MB);
    bf16* Xin = (bf16*)(ws + 8 * MB);   // 16 MB staging, serially reused
    bf16* Ctx = (bf16*)(ws + 8 * MB);   // aliases Xin (dead by attention time)
    bf16* Qb  = (bf16*)(ws + 24 * MB);  // [B,H,S,Dh]
    bf16* Kb  = (bf16*)(ws + 40 * MB);  // [B,H,S,Dh]
    bf16* Vtb = (bf16*)(ws + 56 * MB);  // [B,H,Dh,S]

    dim3 tb(32, 8), tg(32, 32);
    transpose1024<<<tg, tb, 0, stream>>>(W_q, WtQ);
    transpose1024<<<tg, tb, 0, stream>>>(W_k, WtK);
    transpose1024<<<tg, tb, 0, stream>>>(W_v, WtV);
    transpose1024<<<tg, tb, 0, stream>>>(W_o, WtO);

    const int ncv = Mc * Dc;            // 8.39M elems, /8 per thread
    dim3 gg(Dc / 128, Mc / 128);        // (8, 64)

    cvt_bf16<<<ncv / (256 * 8), 256, 0, stream>>>(query, Xin, ncv);
    gemm_bt<1, bf16><<<gg, 256, 0, stream>>>(Xin, WtQ, b_q, Qb, Mc, Dc, Dc);
    cvt_bf16<<<ncv / (256 * 8), 256, 0, stream>>>(key_i, Xin, ncv);
    gemm_bt<1, bf16><<<gg, 256, 0, stream>>>(Xin, WtK, b_k, Kb, Mc, Dc, Dc);
    cvt_bf16<<<ncv / (256 * 8), 256, 0, stream>>>(value, Xin, ncv);
    gemm_bt<2, bf16><<<gg, 256, 0, stream>>>(Xin, WtV, b_v, Vtb, Mc, Dc, Dc);

    attn_fwd<<<dim3(Sc / 128, Bc * Hc), 256, 0, stream>>>(Qb, Kb, Vtb, mask, Ctx);

    gemm_bt<0, float><<<gg, 256, 0, stream>>>(Ctx, WtO, b_o, out, Mc, Dc, Dc);
}